// Round 2
// baseline (350.065 us; speedup 1.0000x reference)
//
#include <hip/hip_runtime.h>

#define Bq   32
#define Lq   4096
#define Eq   1024
#define OUTq 64
#define NW   16   // waves per fused block
#define TG   8    // rows per group

// ---------------------------------------------------------------------------
// K1: vec[b][e] = dot(inputA[b], W1a[e]) + b1a[e] + dot(inputB[b], W1b[e]) + b1b[e]
// Wave per e: W rows loaded ONCE into registers (lane-strided float4),
// loop over b re-reading the 256 KB of inputs from L1/L2. 1024 waves.
// ---------------------------------------------------------------------------
__global__ __launch_bounds__(256) void vec_kernel(
    const float* __restrict__ inA, const float* __restrict__ inB,
    const float* __restrict__ W1a, const float* __restrict__ b1a,
    const float* __restrict__ W1b, const float* __restrict__ b1b,
    float* __restrict__ vec)
{
    int wid  = (blockIdx.x * 256 + threadIdx.x) >> 6;  // = e, 0..1023
    int lane = threadIdx.x & 63;
    if (wid >= Eq) return;
    int e = wid;

    const float4* wa4 = (const float4*)(W1a + (size_t)e * Eq);
    const float4* wb4 = (const float4*)(W1b + (size_t)e * Eq);
    float4 wa[4], wb[4];
#pragma unroll
    for (int j = 0; j < 4; ++j) { wa[j] = wa4[lane + 64 * j]; wb[j] = wb4[lane + 64 * j]; }
    float bias = b1a[e] + b1b[e];

#pragma unroll 4
    for (int b = 0; b < Bq; ++b) {
        const float4* a4  = (const float4*)(inA + (size_t)b * Eq);
        const float4* bb4 = (const float4*)(inB + (size_t)b * Eq);
        float acc = 0.f;
#pragma unroll
        for (int j = 0; j < 4; ++j) {
            float4 a = a4[lane + 64 * j];
            acc += wa[j].x * a.x + wa[j].y * a.y + wa[j].z * a.z + wa[j].w * a.w;
            float4 v = bb4[lane + 64 * j];
            acc += wb[j].x * v.x + wb[j].y * v.y + wb[j].z * v.z + wb[j].w * v.w;
        }
#pragma unroll
        for (int s = 32; s; s >>= 1) acc += __shfl_xor(acc, s, 64);
        if (lane == 0) vec[(size_t)b * Eq + e] = acc + bias;
    }
}

// ---------------------------------------------------------------------------
// K2: fully fused. Grid = 256 blocks: b = blockIdx>>3, blk = blockIdx&7.
// Each iteration handles one GEMM group (8 rows, t<=cache_len: copy to
// ncache + out = row.W2^T + b2) AND one pure-copy group (8 rows,
// t>cache_len) so streaming copy traffic hides the barrier/compute phases.
// Raw s_barrier with lgkmcnt(0) only: global prefetch loads and all global
// stores stay in flight across barriers (no vmcnt(0) drain).
// Lane = output column o; wave w owns K-slice [64w,64w+64), W2 slice in
// 64 VGPRs; rows staged in LDS, consumed via uniform-address (broadcast)
// ds_read_b128; cross-wave reduce through LDS. 2 barriers/iter.
// ---------------------------------------------------------------------------
__global__ __launch_bounds__(1024, 4) void fused_kernel(
    const float* __restrict__ cache, const float* __restrict__ vec,
    const float* __restrict__ W2, const float* __restrict__ b2,
    float* __restrict__ outp, float* __restrict__ ncache,
    int cache_len, int ngg, int ncg)
{
    const int rows_out = cache_len + 1;     // 2049
    const int tid = threadIdx.x;
    const int w = tid >> 6, lane = tid & 63;
    const int b   = blockIdx.x >> 3;
    const int blk = blockIdx.x & 7;

    __shared__ float rowbuf[TG][Eq];        // 32 KB
    __shared__ float part[NW][TG * 64];     // 32 KB

    // W2 slice: lane (=o) holds W2[o][64w + 4j .. +3], j=0..15
    float4 w2r[16];
#pragma unroll
    for (int j = 0; j < 16; ++j)
        w2r[j] = *(const float4*)(W2 + (size_t)lane * Eq + 64 * w + 4 * j);

    const float bias = b2[tid & 63];

    const int rsub = tid >> 7;   // 0..7 : row within group
    const int c    = tid & 127;  // covers float4 cols c and c+128

    const float* cb = cache  + (size_t)b * Lq * Eq;
    float*       nb = ncache + (size_t)b * Lq * Eq;
    const float* vb = vec    + (size_t)b * Eq;

    float4 gld0 = {0,0,0,0}, gld1 = {0,0,0,0}, cld0 = {0,0,0,0}, cld1 = {0,0,0,0};

    auto fetch_g = [&](int g) {
        int t = TG * g + rsub;
        if (g < ngg && t <= cache_len) {
            const float* src = (t == cache_len) ? vb : (cb + (size_t)t * Eq);
            gld0 = *(const float4*)(src + 4 * c);
            gld1 = *(const float4*)(src + 4 * (c + 128));
        }
    };
    auto fetch_c = [&](int cg) {
        int t = rows_out + TG * cg + rsub;
        if (cg < ncg && t < Lq) {
            const float* src = cb + (size_t)t * Eq;
            cld0 = *(const float4*)(src + 4 * c);
            cld1 = *(const float4*)(src + 4 * (c + 128));
        }
    };

    fetch_g(blk);
    fetch_c(blk);

    for (int g = blk; g < ngg; g += 8) {
        // ---- phase 1: stores for current group + LDS stage + prefetch next
        int t = TG * g + rsub;
        if (t <= cache_len) {
            float* dst = nb + (size_t)t * Eq;
            *(float4*)(dst + 4 * c)          = gld0;
            *(float4*)(dst + 4 * (c + 128))  = gld1;
            *(float4*)(&rowbuf[rsub][4 * c])         = gld0;
            *(float4*)(&rowbuf[rsub][4 * (c + 128)]) = gld1;
        }
        int tc = rows_out + TG * g + rsub;
        if (g < ncg && tc < Lq) {
            float* dst = nb + (size_t)tc * Eq;
            *(float4*)(dst + 4 * c)         = cld0;
            *(float4*)(dst + 4 * (c + 128)) = cld1;
        }

        fetch_g(g + 8);
        fetch_c(g + 8);

        // barrier A: rowbuf ready. LDS drained, global ops stay in flight.
        asm volatile("s_waitcnt lgkmcnt(0)\n\ts_barrier" ::: "memory");

        // ---- phase 2: per-wave K-slice FMAs (broadcast ds_read_b128)
#pragma unroll
        for (int r = 0; r < TG; ++r) {
            float acc = 0.f;
#pragma unroll
            for (int j = 0; j < 16; ++j) {
                float4 rv = *(const float4*)(&rowbuf[r][64 * w + 4 * j]);
                acc += rv.x * w2r[j].x + rv.y * w2r[j].y +
                       rv.z * w2r[j].z + rv.w * w2r[j].w;
            }
            part[w][r * 64 + lane] = acc;
        }

        // barrier B: partials ready.
        asm volatile("s_waitcnt lgkmcnt(0)\n\ts_barrier" ::: "memory");

        // ---- phase 3: cross-wave reduce + out store.
        // (No barrier C needed: next iter's barrier A orders part reads
        //  before next iter's part writes, and rowbuf writes are after B.)
        if (tid < TG * 64) {
            int rr = tid >> 6, o = tid & 63;
            int trow = TG * g + rr;
            if (trow < rows_out) {
                float s = 0.f;
#pragma unroll
                for (int ww = 0; ww < NW; ++ww) s += part[ww][tid];
                outp[((size_t)b * rows_out + trow) * OUTq + o] = s + bias;
            }
        }
    }
}

// ---------------------------------------------------------------------------
extern "C" void kernel_launch(void* const* d_in, const int* in_sizes, int n_in,
                              void* d_out, int out_size, void* d_ws, size_t ws_size,
                              hipStream_t stream)
{
    const float* inA   = (const float*)d_in[0];
    const float* inB   = (const float*)d_in[1];
    const float* cache = (const float*)d_in[2];
    const float* W1a   = (const float*)d_in[3];
    const float* b1a   = (const float*)d_in[4];
    const float* W1b   = (const float*)d_in[5];
    const float* b1b   = (const float*)d_in[6];
    const float* W2    = (const float*)d_in[7];
    const float* b2v   = (const float*)d_in[8];

    float* outp = (float*)d_out;
    // out = (B, cache_len+1, OUT) then new_cache (B, L, E), f32, concat flat.
    int rows_out  = (out_size - Bq * Lq * Eq) / (Bq * OUTq);  // cache_len + 1
    int cache_len = rows_out - 1;                             // 2048
    float* ncache = outp + (size_t)Bq * rows_out * OUTq;
    float* vecbuf = (float*)d_ws;                             // 32*1024 f32

    int ngg = (rows_out + TG - 1) / TG;            // 257 gemm groups / batch
    int ncg = (Lq - rows_out + TG - 1) / TG;       // 256 copy groups / batch

    vec_kernel<<<dim3(256), dim3(256), 0, stream>>>(inA, inB, W1a, b1a, W1b, b1b, vecbuf);

    fused_kernel<<<dim3(256), dim3(1024), 0, stream>>>(cache, vecbuf, W2, b2v,
                                                       outp, ncache,
                                                       cache_len, ngg, ncg);
}